// Round 10
// baseline (250.922 us; speedup 1.0000x reference)
//
#include <hip/hip_runtime.h>

// MHA: D_MODEL=1024, D_K=64, H=16, N=2, T=2048. fp32 I/O, bf16 MFMA internals.
// R10: software-pipelined K-loops in all 3 MFMA kernels: double-buffered LDS,
// raw __builtin_amdgcn_s_barrier + manual s_waitcnt vmcnt(L) (waits only the
// CURRENT tile's loads; next tile's global_load_lds stay in flight across the
// barrier). This removes the vmcnt(0) drain that exposed ~300cyc L2 latency
// every iteration (R8/R9 GEMMs stuck at ~300 TF, flash 38% idle).
// Flash: mask hoisted to LDS in prologue (keeps loop vmcnt counting pure).
// waitcnt imm: vmcnt=N (N<16): 0xF70|N  (expcnt=7, lgkmcnt=15 unconstrained).
// ws >= 32MB: bf16 k,q,v + 4 transposed bf16 weights. Intermediates in dead
// fp32 input buffers. XOR-swizzled LDS (R9) kept: conflict-free + DMA-legal.

typedef __bf16 bf16;
typedef __bf16 bf16x8 __attribute__((ext_vector_type(8)));
typedef __bf16 bf16x4 __attribute__((ext_vector_type(4)));
typedef float f32x4 __attribute__((ext_vector_type(4)));

#define MFMA16(a, b, c) __builtin_amdgcn_mfma_f32_16x16x32_bf16((a), (b), (c), 0, 0, 0)

__device__ __forceinline__ void load_lds16(const bf16* g, bf16* l) {
  __builtin_amdgcn_global_load_lds(
      (const __attribute__((address_space(1))) unsigned int*)g,
      (__attribute__((address_space(3))) unsigned int*)l, 16, 0, 0);
}

__device__ __forceinline__ bf16x8 cvt8(const float* __restrict__ p) {
  const f32x4 a = *(const f32x4*)p;
  const f32x4 b = *(const f32x4*)(p + 4);
  bf16x8 r;
  r[0] = (bf16)a[0]; r[1] = (bf16)a[1]; r[2] = (bf16)a[2]; r[3] = (bf16)a[3];
  r[4] = (bf16)b[0]; r[5] = (bf16)b[1]; r[6] = (bf16)b[2]; r[7] = (bf16)b[3];
  return r;
}

// ---------------------------------------------------------------------------
// Prepass 1: k,q,v (4M fp32 each) -> bf16.
// ---------------------------------------------------------------------------
__global__ __launch_bounds__(256) void convert3(const float* __restrict__ a,
                                                const float* __restrict__ b,
                                                const float* __restrict__ c,
                                                bf16* __restrict__ oa,
                                                bf16* __restrict__ ob,
                                                bf16* __restrict__ oc) {
  const size_t i = ((size_t)blockIdx.x * 256 + threadIdx.x) * 8;
  const int which = (int)(i >> 22);
  const size_t off = i & ((size_t)(1u << 22) - 1);
  const float* src = which == 0 ? a : (which == 1 ? b : c);
  bf16* dst = which == 0 ? oa : (which == 1 ? ob : oc);
  *(bf16x8*)&dst[off] = cvt8(&src[off]);
}

// ---------------------------------------------------------------------------
// Prepass 2: W [1024k x 1024n] fp32 -> WT [n][k] bf16. grid (16,16,4).
// ---------------------------------------------------------------------------
__global__ __launch_bounds__(256) void transposeW(
    const float* __restrict__ W0, const float* __restrict__ W1,
    const float* __restrict__ W2, const float* __restrict__ W3,
    bf16* __restrict__ T0, bf16* __restrict__ T1, bf16* __restrict__ T2,
    bf16* __restrict__ T3) {
  __shared__ bf16 t[64 * 72];
  const int z = blockIdx.z;
  const float* W = z == 0 ? W0 : (z == 1 ? W1 : (z == 2 ? W2 : W3));
  bf16* T = z == 0 ? T0 : (z == 1 ? T1 : (z == 2 ? T2 : T3));
  const int kBase = blockIdx.y * 64, nBase = blockIdx.x * 64;
  const int tid = threadIdx.x;
  const int row = tid >> 2, cs = (tid & 3) * 16;

  const float* src = &W[(size_t)(kBase + row) * 1024 + nBase + cs];
  *(bf16x8*)&t[row * 72 + cs] = cvt8(src);
  *(bf16x8*)&t[row * 72 + cs + 8] = cvt8(src + 8);
  __syncthreads();

  const int n = tid >> 2, ks = (tid & 3) * 16;
  bf16 buf[16];
#pragma unroll
  for (int j = 0; j < 16; ++j) buf[j] = t[(ks + j) * 72 + n];
  bf16* dst = &T[(size_t)(nBase + n) * 1024 + kBase + ks];
  *(bf16x8*)&dst[0] = *(bf16x8*)&buf[0];
  *(bf16x8*)&dst[8] = *(bf16x8*)&buf[8];
}

// ---------------------------------------------------------------------------
// gemm_qkv: fused K/V/Q projections, software-pipelined.
// z=0: K (bh,t,d). z=1: Vt (bh,d,t) via LDS transpose. z=2: Q, *0.125.
// BM=BN=128, BK=64; dbuf LDS = 64KB (2 blocks/CU); 32 MFMA/iter/wave.
// ---------------------------------------------------------------------------
__global__ __launch_bounds__(256) void gemm_qkv(
    const bf16* __restrict__ kb, const bf16* __restrict__ vb,
    const bf16* __restrict__ qb, const bf16* __restrict__ WkT,
    const bf16* __restrict__ WvT, const bf16* __restrict__ WqT,
    const float* __restrict__ bk, const float* __restrict__ bv,
    const float* __restrict__ bq, bf16* __restrict__ K_buf,
    bf16* __restrict__ Vt_buf, bf16* __restrict__ Q_buf) {
  // S: As0 [0,8192) As1 [8192,16384) Ws0 [16384,24576) Ws1 [24576,32768)
  __shared__ __align__(16) bf16 S[32768];
  const int tid = threadIdx.x;
  const int lane = tid & 63, w = tid >> 6;
  const int l15 = lane & 15, quad = lane >> 4;
  const int z = blockIdx.z;
  const bf16* X = z == 0 ? kb : (z == 1 ? vb : qb);
  const bf16* WT = z == 0 ? WkT : (z == 1 ? WvT : WqT);
  const float* B = z == 0 ? bk : (z == 1 ? bv : bq);
  const int mBase = blockIdx.y * 128, nBase = blockIdx.x * 128;
  const int wm = (w >> 1) * 64, wn = (w & 1) * 64;

  const int r8 = tid >> 3;
  const int jg = ((tid & 7) ^ (r8 & 7)) * 8;
  const int sw = l15 & 7;

  f32x4 acc[4][4] = {};

  auto issue8 = [&](int buf, int k0) {
#pragma unroll
    for (int i = 0; i < 4; ++i) {
      const int row = r8 + i * 32;
      load_lds16(&X[(size_t)(mBase + row) * 1024 + k0 + jg],
                 &S[buf * 8192 + (tid + i * 256) * 8]);
      load_lds16(&WT[(size_t)(nBase + row) * 1024 + k0 + jg],
                 &S[16384 + buf * 8192 + (tid + i * 256) * 8]);
    }
  };
  auto compute = [&](int cur) {
    const bf16* Ac = &S[cur * 8192];
    const bf16* Wc = &S[16384 + cur * 8192];
#pragma unroll
    for (int k2 = 0; k2 < 2; ++k2) {
      const int col = ((k2 * 4 + quad) ^ sw) * 8;
      bf16x8 a[4], bb[4];
#pragma unroll
      for (int mt = 0; mt < 4; ++mt)
        a[mt] = *(const bf16x8*)&Ac[(wm + mt * 16 + l15) * 64 + col];
#pragma unroll
      for (int nt = 0; nt < 4; ++nt)
        bb[nt] = *(const bf16x8*)&Wc[(wn + nt * 16 + l15) * 64 + col];
#pragma unroll
      for (int mt = 0; mt < 4; ++mt)
#pragma unroll
        for (int nt = 0; nt < 4; ++nt)
          acc[mt][nt] = MFMA16(a[mt], bb[nt], acc[mt][nt]);
    }
  };

  issue8(0, 0);
  for (int it = 0; it < 15; ++it) {
    issue8((it + 1) & 1, (it + 1) * 64);
    __builtin_amdgcn_s_waitcnt(0xF78);  // vmcnt(8): current tile done
    __builtin_amdgcn_s_barrier();
    compute(it & 1);
    __builtin_amdgcn_s_barrier();  // reads done before buf reuse
  }
  __builtin_amdgcn_s_waitcnt(0xF70);  // vmcnt(0)
  __builtin_amdgcn_s_barrier();
  compute(1);

  // Epilogue. C layout: col = l15 (n), row = quad*4+r (m).
  if (z != 1) {
    const float scale = (z == 2) ? 0.125f : 1.0f;
    bf16* o = (z == 0) ? K_buf : Q_buf;
#pragma unroll
    for (int nt = 0; nt < 4; ++nt) {
      const int n = nBase + wn + nt * 16 + l15;
      const float bias = B[n];
      const int h = n >> 6, d = n & 63;
#pragma unroll
      for (int mt = 0; mt < 4; ++mt)
#pragma unroll
        for (int r = 0; r < 4; ++r) {
          const int m = mBase + wm + mt * 16 + quad * 4 + r;
          const int b = m >> 11, t = m & 2047;
          o[((size_t)(b * 16 + h) * 2048 + t) * 64 + d] =
              (bf16)((acc[mt][nt][r] + bias) * scale);
        }
    }
  } else {
    // Vt: transpose each wave's 64x64 C-tile in LDS, store b128 along t.
    __syncthreads();
    bf16* Tb = &S[w * 4608];  // 64 x 72
#pragma unroll
    for (int nt = 0; nt < 4; ++nt) {
      const int n = nBase + wn + nt * 16 + l15;
      const float bias = B[n];
#pragma unroll
      for (int mt = 0; mt < 4; ++mt) {
        bf16x4 pk;
#pragma unroll
        for (int r = 0; r < 4; ++r) pk[r] = (bf16)(acc[mt][nt][r] + bias);
        *(bf16x4*)&Tb[(nt * 16 + l15) * 72 + mt * 16 + quad * 4] = pk;
      }
    }
    const int b = mBase >> 11;
#pragma unroll
    for (int i = 0; i < 8; ++i) {
      const int dl = i * 8 + (lane >> 3), ts = (lane & 7) * 8;
      const bf16x8 vv = *(const bf16x8*)&Tb[dl * 72 + ts];
      const int n = nBase + wn + dl;
      const int h = n >> 6, d = n & 63;
      const int t = (mBase + wm + ts) & 2047;
      *(bf16x8*)&Vt_buf[((size_t)(b * 16 + h) * 64 + d) * 2048 + t] = vv;
    }
  }
}

// ---------------------------------------------------------------------------
// gemm_out: out = A @ WoT^T + bo -> fp32. BM=128, BN=64, BK=64, pipelined.
// ---------------------------------------------------------------------------
__global__ __launch_bounds__(256) void gemm_out(const bf16* __restrict__ X,
                                                const bf16* __restrict__ WT,
                                                const float* __restrict__ B,
                                                float* __restrict__ out) {
  // As0 [0,8192) As1 [8192,16384) Ws0 [16384,20480) Ws1 [20480,24576)
  __shared__ __align__(16) bf16 S[24576];
  const int tid = threadIdx.x;
  const int lane = tid & 63, w = tid >> 6;
  const int l15 = lane & 15, quad = lane >> 4;
  const int mBase = blockIdx.y * 128, nBase = blockIdx.x * 64;
  const int wm = (w >> 1) * 64, wn = (w & 1) * 32;

  const int r8 = tid >> 3;
  const int jg = ((tid & 7) ^ (r8 & 7)) * 8;
  const int sw = l15 & 7;

  f32x4 acc[4][2] = {};

  auto issue6 = [&](int buf, int k0) {
#pragma unroll
    for (int i = 0; i < 4; ++i)
      load_lds16(&X[(size_t)(mBase + r8 + i * 32) * 1024 + k0 + jg],
                 &S[buf * 8192 + (tid + i * 256) * 8]);
#pragma unroll
    for (int i = 0; i < 2; ++i)
      load_lds16(&WT[(size_t)(nBase + r8 + i * 32) * 1024 + k0 + jg],
                 &S[16384 + buf * 4096 + (tid + i * 256) * 8]);
  };
  auto compute = [&](int cur) {
    const bf16* Ac = &S[cur * 8192];
    const bf16* Wc = &S[16384 + cur * 4096];
#pragma unroll
    for (int k2 = 0; k2 < 2; ++k2) {
      const int col = ((k2 * 4 + quad) ^ sw) * 8;
      bf16x8 a[4], bb[2];
#pragma unroll
      for (int mt = 0; mt < 4; ++mt)
        a[mt] = *(const bf16x8*)&Ac[(wm + mt * 16 + l15) * 64 + col];
#pragma unroll
      for (int nt = 0; nt < 2; ++nt)
        bb[nt] = *(const bf16x8*)&Wc[(wn + nt * 16 + l15) * 64 + col];
#pragma unroll
      for (int mt = 0; mt < 4; ++mt)
#pragma unroll
        for (int nt = 0; nt < 2; ++nt)
          acc[mt][nt] = MFMA16(a[mt], bb[nt], acc[mt][nt]);
    }
  };

  issue6(0, 0);
  for (int it = 0; it < 15; ++it) {
    issue6((it + 1) & 1, (it + 1) * 64);
    __builtin_amdgcn_s_waitcnt(0xF76);  // vmcnt(6)
    __builtin_amdgcn_s_barrier();
    compute(it & 1);
    __builtin_amdgcn_s_barrier();
  }
  __builtin_amdgcn_s_waitcnt(0xF70);
  __builtin_amdgcn_s_barrier();
  compute(1);

#pragma unroll
  for (int nt = 0; nt < 2; ++nt) {
    const int n = nBase + wn + nt * 16 + l15;
    const float bias = B[n];
#pragma unroll
    for (int mt = 0; mt < 4; ++mt)
#pragma unroll
      for (int r = 0; r < 4; ++r) {
        const int m = mBase + wm + mt * 16 + quad * 4 + r;
        out[(size_t)m * 1024 + n] = acc[mt][nt][r] + bias;
      }
  }
}

// ---------------------------------------------------------------------------
// flash_attn (S^T/O^T, pipelined): mask hoisted to LDS in prologue; K/V
// double-buffered; fixed-reference softmax (m=0); per-lane scalar row sum.
// ---------------------------------------------------------------------------
__global__ __launch_bounds__(256) void flash_attn(const bf16* __restrict__ Q,
                                                  const bf16* __restrict__ K,
                                                  const bf16* __restrict__ Vt,
                                                  const int* __restrict__ mask,
                                                  bf16* __restrict__ A) {
  __shared__ __align__(16) bf16 KsB[2 * 4096];  // [key][d] swizzled, dbuf
  __shared__ __align__(16) bf16 VsB[2 * 4096];  // [d][key] swizzled, dbuf
  __shared__ __align__(16) bf16 Ps[64 * 72];    // [q][key], wave-private rows
  __shared__ __align__(16) int mskAll[2048];

  const int tid = threadIdx.x;
  const int lane = tid & 63, w = tid >> 6;
  const int l15 = lane & 15, quad = lane >> 4;
  const int bh = blockIdx.y;
  const int b = bh >> 4, h = bh & 15;
  const int qt = blockIdx.x * 64;

  const int r8 = tid >> 3;
  const int jg = ((tid & 7) ^ (r8 & 7)) * 8;
  const int sw = l15 & 7;

  // Prologue: Q frags (B-layout), full mask row -> LDS.
  const size_t qbase = ((size_t)bh * 2048 + qt + w * 16 + l15) * 64;
  const bf16x8 bq0 = *(const bf16x8*)&Q[qbase + quad * 8];
  const bf16x8 bq1 = *(const bf16x8*)&Q[qbase + 32 + quad * 8];
  {
    const int4* mrow = (const int4*)(mask + b * 2048);
    *(int4*)&mskAll[tid * 8] = mrow[tid * 2];
    *(int4*)&mskAll[tid * 8 + 4] = mrow[tid * 2 + 1];
  }
  __syncthreads();  // full drain OK here (pre-pipeline)

  f32x4 o[4] = {};
  float rs = 0.0f;

  auto issue4 = [&](int buf, int kt) {
#pragma unroll
    for (int i = 0; i < 2; ++i) {
      const int row = r8 + i * 32;
      load_lds16(&K[((size_t)bh * 2048 + kt + row) * 64 + jg],
                 &KsB[buf * 4096 + (tid + i * 256) * 8]);
      load_lds16(&Vt[((size_t)bh * 64 + row) * 2048 + kt + jg],
                 &VsB[buf * 4096 + (tid + i * 256) * 8]);
    }
  };
  auto tile = [&](int cur, int kt) {
    const bf16* Kc = &KsB[cur * 4096];
    const bf16* Vc = &VsB[cur * 4096];
#pragma unroll
    for (int nt = 0; nt < 4; ++nt) {
      const bf16x8 ak0 = *(const bf16x8*)&Kc[(nt * 16 + l15) * 64 + ((quad ^ sw) * 8)];
      const bf16x8 ak1 = *(const bf16x8*)&Kc[(nt * 16 + l15) * 64 + (((4 + quad) ^ sw) * 8)];
      f32x4 s4 = {};
      s4 = MFMA16(ak0, bq0, s4);
      s4 = MFMA16(ak1, bq1, s4);
      const int4 mi = *(const int4*)&mskAll[kt + nt * 16 + quad * 4];
      const float p0 = mi.x ? __expf(s4[0]) : 0.0f;
      const float p1 = mi.y ? __expf(s4[1]) : 0.0f;
      const float p2 = mi.z ? __expf(s4[2]) : 0.0f;
      const float p3 = mi.w ? __expf(s4[3]) : 0.0f;
      rs += (p0 + p1) + (p2 + p3);
      bf16x4 pk;
      pk[0] = (bf16)p0; pk[1] = (bf16)p1; pk[2] = (bf16)p2; pk[3] = (bf16)p3;
      *(bf16x4*)&Ps[(w * 16 + l15) * 72 + nt * 16 + quad * 4] = pk;
    }
    // No barrier: Ps rows wave-private, DS in-order per wave.
#pragma unroll
    for (int ks = 0; ks < 2; ++ks) {
      const bf16x8 bp = *(const bf16x8*)&Ps[(w * 16 + l15) * 72 + ks * 32 + quad * 8];
#pragma unroll
      for (int mt = 0; mt < 4; ++mt) {
        const bf16x8 av =
            *(const bf16x8*)&Vc[(mt * 16 + l15) * 64 + (((ks * 4 + quad) ^ sw) * 8)];
        o[mt] = MFMA16(av, bp, o[mt]);
      }
    }
  };

  issue4(0, 0);
  for (int it = 0; it < 31; ++it) {
    issue4((it + 1) & 1, (it + 1) * 64);
    __builtin_amdgcn_s_waitcnt(0xF74);  // vmcnt(4): current K/V tile done
    __builtin_amdgcn_s_barrier();
    tile(it & 1, it * 64);
    __builtin_amdgcn_s_barrier();
  }
  __builtin_amdgcn_s_waitcnt(0xF70);
  __builtin_amdgcn_s_barrier();
  tile(1, 31 * 64);

  // Row sum over quads; normalize; O^T epilogue (b64 packs along d).
  rs += __shfl_xor(rs, 16);
  rs += __shfl_xor(rs, 32);
  const float inv = rs > 0.0f ? 1.0f / rs : 0.0f;

  const int t = qt + w * 16 + l15;
  const size_t base = ((size_t)b * 2048 + t) * 1024 + h * 64;
#pragma unroll
  for (int mt = 0; mt < 4; ++mt) {
    bf16x4 ov;
#pragma unroll
    for (int r = 0; r < 4; ++r) ov[r] = (bf16)(o[mt][r] * inv);
    *(bf16x4*)&A[base + mt * 16 + quad * 4] = ov;
  }
}

// ---------------------------------------------------------------------------
extern "C" void kernel_launch(void* const* d_in, const int* in_sizes, int n_in,
                              void* d_out, int out_size, void* d_ws, size_t ws_size,
                              hipStream_t stream) {
  const float* k = (const float*)d_in[0];
  const float* q = (const float*)d_in[1];
  const float* v = (const float*)d_in[2];
  const int* mask = (const int*)d_in[3];
  const float* Wk = (const float*)d_in[4];
  const float* bk = (const float*)d_in[5];
  const float* Wq = (const float*)d_in[6];
  const float* bq = (const float*)d_in[7];
  const float* Wv = (const float*)d_in[8];
  const float* bv = (const float*)d_in[9];
  const float* Wo = (const float*)d_in[10];
  const float* bo = (const float*)d_in[11];

  const size_t ELEMS = (size_t)4 * 1024 * 1024;
  const size_t WELEMS = (size_t)1024 * 1024;

  bf16* kb = (bf16*)d_ws;
  bf16* qb = kb + ELEMS;
  bf16* vb = qb + ELEMS;
  bf16* WkT = vb + ELEMS;
  bf16* WqT = WkT + WELEMS;
  bf16* WvT = WqT + WELEMS;
  bf16* WoT = WvT + WELEMS;

  bf16* K_buf = (bf16*)d_in[0];
  bf16* Q_buf = (bf16*)d_in[0] + ELEMS;
  bf16* Vt_buf = (bf16*)d_in[2];
  bf16* A_buf = (bf16*)d_in[2] + ELEMS;

  convert3<<<6144, 256, 0, stream>>>(k, q, v, kb, qb, vb);
  transposeW<<<dim3(16, 16, 4), 256, 0, stream>>>(Wk, Wq, Wv, Wo,
                                                  WkT, WqT, WvT, WoT);
  gemm_qkv<<<dim3(8, 32, 3), 256, 0, stream>>>(kb, vb, qb, WkT, WvT, WqT,
                                               bk, bv, bq, K_buf, Vt_buf, Q_buf);
  flash_attn<<<dim3(32, 32), 256, 0, stream>>>(Q_buf, K_buf, Vt_buf, mask, A_buf);
  gemm_out<<<dim3(16, 32), 256, 0, stream>>>(A_buf, WoT, bo, (float*)d_out);
}

// Round 11
// 242.356 us; speedup vs baseline: 1.0353x; 1.0353x over previous
//
#include <hip/hip_runtime.h>

// MHA: D_MODEL=1024, D_K=64, H=16, N=2, T=2048. fp32 I/O, bf16 MFMA internals.
// R11: discriminating experiment on the GEMM plateau (~200 TF insensitive to
// BK/swizzle/pipelining). gemm_qkv rebuilt BM=128 BN=64 BK=64, single-buffer
// 24KB LDS, plain __syncthreads -> grid 1536 = 6 blocks/CU (2x TLP, but also
// 1.5x L2 traffic): latency-starvation theory predicts WIN, traffic theory
// predicts LOSS. flash + gemm_out reverted to R9 exact (R10 pipeline was
// neutral-to-negative: occupancy loss cancelled latency win).
// ws >= 32MB: bf16 k,q,v + 4 transposed bf16 weights. Intermediates in dead
// fp32 input buffers. XOR-swizzled LDS everywhere (conflict-free + DMA-legal).

typedef __bf16 bf16;
typedef __bf16 bf16x8 __attribute__((ext_vector_type(8)));
typedef __bf16 bf16x4 __attribute__((ext_vector_type(4)));
typedef float f32x4 __attribute__((ext_vector_type(4)));

#define MFMA16(a, b, c) __builtin_amdgcn_mfma_f32_16x16x32_bf16((a), (b), (c), 0, 0, 0)

__device__ __forceinline__ void load_lds16(const bf16* g, bf16* l) {
  __builtin_amdgcn_global_load_lds(
      (const __attribute__((address_space(1))) unsigned int*)g,
      (__attribute__((address_space(3))) unsigned int*)l, 16, 0, 0);
}

__device__ __forceinline__ bf16x8 cvt8(const float* __restrict__ p) {
  const f32x4 a = *(const f32x4*)p;
  const f32x4 b = *(const f32x4*)(p + 4);
  bf16x8 r;
  r[0] = (bf16)a[0]; r[1] = (bf16)a[1]; r[2] = (bf16)a[2]; r[3] = (bf16)a[3];
  r[4] = (bf16)b[0]; r[5] = (bf16)b[1]; r[6] = (bf16)b[2]; r[7] = (bf16)b[3];
  return r;
}

// ---------------------------------------------------------------------------
// Prepass 1: k,q,v (4M fp32 each) -> bf16.
// ---------------------------------------------------------------------------
__global__ __launch_bounds__(256) void convert3(const float* __restrict__ a,
                                                const float* __restrict__ b,
                                                const float* __restrict__ c,
                                                bf16* __restrict__ oa,
                                                bf16* __restrict__ ob,
                                                bf16* __restrict__ oc) {
  const size_t i = ((size_t)blockIdx.x * 256 + threadIdx.x) * 8;
  const int which = (int)(i >> 22);
  const size_t off = i & ((size_t)(1u << 22) - 1);
  const float* src = which == 0 ? a : (which == 1 ? b : c);
  bf16* dst = which == 0 ? oa : (which == 1 ? ob : oc);
  *(bf16x8*)&dst[off] = cvt8(&src[off]);
}

// ---------------------------------------------------------------------------
// Prepass 2: W [1024k x 1024n] fp32 -> WT [n][k] bf16. grid (16,16,4).
// ---------------------------------------------------------------------------
__global__ __launch_bounds__(256) void transposeW(
    const float* __restrict__ W0, const float* __restrict__ W1,
    const float* __restrict__ W2, const float* __restrict__ W3,
    bf16* __restrict__ T0, bf16* __restrict__ T1, bf16* __restrict__ T2,
    bf16* __restrict__ T3) {
  __shared__ bf16 t[64 * 72];
  const int z = blockIdx.z;
  const float* W = z == 0 ? W0 : (z == 1 ? W1 : (z == 2 ? W2 : W3));
  bf16* T = z == 0 ? T0 : (z == 1 ? T1 : (z == 2 ? T2 : T3));
  const int kBase = blockIdx.y * 64, nBase = blockIdx.x * 64;
  const int tid = threadIdx.x;
  const int row = tid >> 2, cs = (tid & 3) * 16;

  const float* src = &W[(size_t)(kBase + row) * 1024 + nBase + cs];
  *(bf16x8*)&t[row * 72 + cs] = cvt8(src);
  *(bf16x8*)&t[row * 72 + cs + 8] = cvt8(src + 8);
  __syncthreads();

  const int n = tid >> 2, ks = (tid & 3) * 16;
  bf16 buf[16];
#pragma unroll
  for (int j = 0; j < 16; ++j) buf[j] = t[(ks + j) * 72 + n];
  bf16* dst = &T[(size_t)(nBase + n) * 1024 + kBase + ks];
  *(bf16x8*)&dst[0] = *(bf16x8*)&buf[0];
  *(bf16x8*)&dst[8] = *(bf16x8*)&buf[8];
}

// ---------------------------------------------------------------------------
// gemm_qkv: fused K/V/Q projections. BM=128, BN=64 (one head per block),
// BK=64; 4 waves, wave tile 64x32 (4x2 acc, 16 MFMA/iter); 24KB LDS ->
// 6 blocks/CU; grid (16,32,3) = 1536 blocks.
// z=0: K (bh,t,d). z=1: Vt (bh,d,t) via LDS transpose. z=2: Q, *0.125.
// ---------------------------------------------------------------------------
__global__ __launch_bounds__(256) void gemm_qkv(
    const bf16* __restrict__ kb, const bf16* __restrict__ vb,
    const bf16* __restrict__ qb, const bf16* __restrict__ WkT,
    const bf16* __restrict__ WvT, const bf16* __restrict__ WqT,
    const float* __restrict__ bk, const float* __restrict__ bv,
    const float* __restrict__ bq, bf16* __restrict__ K_buf,
    bf16* __restrict__ Vt_buf, bf16* __restrict__ Q_buf) {
  // S: As = [0, 8192) [m][k], Ws = [8192, 12288) [n][k]. 24 KB.
  __shared__ __align__(16) bf16 S[12288];
  bf16* As = S;
  bf16* Ws = S + 8192;
  const int tid = threadIdx.x;
  const int lane = tid & 63, w = tid >> 6;
  const int l15 = lane & 15, quad = lane >> 4;
  const int z = blockIdx.z;
  const bf16* X = z == 0 ? kb : (z == 1 ? vb : qb);
  const bf16* WT = z == 0 ? WkT : (z == 1 ? WvT : WqT);
  const float* B = z == 0 ? bk : (z == 1 ? bv : bq);
  const int mBase = blockIdx.y * 128, nBase = blockIdx.x * 64;
  const int wm = (w >> 1) * 64, wn = (w & 1) * 32;

  const int r8 = tid >> 3;                    // 0..31
  const int jg = ((tid & 7) ^ (r8 & 7)) * 8;  // swizzled col seg
  const int sw = l15 & 7;

  f32x4 acc[4][2] = {};

  for (int k0 = 0; k0 < 1024; k0 += 64) {
    __syncthreads();
#pragma unroll
    for (int i = 0; i < 4; ++i)
      load_lds16(&X[(size_t)(mBase + r8 + i * 32) * 1024 + k0 + jg],
                 &As[(tid + i * 256) * 8]);
#pragma unroll
    for (int i = 0; i < 2; ++i)
      load_lds16(&WT[(size_t)(nBase + r8 + i * 32) * 1024 + k0 + jg],
                 &Ws[(tid + i * 256) * 8]);
    __syncthreads();

#pragma unroll
    for (int k2 = 0; k2 < 2; ++k2) {
      const int col = ((k2 * 4 + quad) ^ sw) * 8;
      bf16x8 a[4], bb[2];
#pragma unroll
      for (int mt = 0; mt < 4; ++mt)
        a[mt] = *(const bf16x8*)&As[(wm + mt * 16 + l15) * 64 + col];
#pragma unroll
      for (int nt = 0; nt < 2; ++nt)
        bb[nt] = *(const bf16x8*)&Ws[(wn + nt * 16 + l15) * 64 + col];
#pragma unroll
      for (int mt = 0; mt < 4; ++mt)
#pragma unroll
        for (int nt = 0; nt < 2; ++nt)
          acc[mt][nt] = MFMA16(a[mt], bb[nt], acc[mt][nt]);
    }
  }

  // Epilogue. C layout: col = l15 (n-local), row = quad*4+r (m-local).
  const int h = nBase >> 6;  // BN=64: one head per block
  if (z != 1) {
    const float scale = (z == 2) ? 0.125f : 1.0f;
    bf16* o = (z == 0) ? K_buf : Q_buf;
#pragma unroll
    for (int nt = 0; nt < 2; ++nt) {
      const int n = nBase + wn + nt * 16 + l15;
      const float bias = B[n];
      const int d = n & 63;
#pragma unroll
      for (int mt = 0; mt < 4; ++mt)
#pragma unroll
        for (int r = 0; r < 4; ++r) {
          const int m = mBase + wm + mt * 16 + quad * 4 + r;
          const int b = m >> 11, t = m & 2047;
          o[((size_t)(b * 16 + h) * 2048 + t) * 64 + d] =
              (bf16)((acc[mt][nt][r] + bias) * scale);
        }
    }
  } else {
    // Vt: transpose each wave's 64(t)x32(d) C-tile in LDS, store b128 along t.
    __syncthreads();  // frag reads of S done
    bf16* Tb = &S[w * 2304];  // 32 x 72
#pragma unroll
    for (int nt = 0; nt < 2; ++nt) {
      const int n = nBase + wn + nt * 16 + l15;
      const float bias = B[n];
#pragma unroll
      for (int mt = 0; mt < 4; ++mt) {
        bf16x4 pk;
#pragma unroll
        for (int r = 0; r < 4; ++r) pk[r] = (bf16)(acc[mt][nt][r] + bias);
        *(bf16x4*)&Tb[(nt * 16 + l15) * 72 + mt * 16 + quad * 4] = pk;
      }
    }
    // same-wave in-order LDS: no barrier needed
    const int b = mBase >> 11;  // 128-row tile never straddles batch
#pragma unroll
    for (int i = 0; i < 4; ++i) {
      const int dl = i * 8 + (lane >> 3), ts = (lane & 7) * 8;
      const bf16x8 vv = *(const bf16x8*)&Tb[dl * 72 + ts];
      const int d = wn + dl;
      const int t = (mBase + wm + ts) & 2047;
      *(bf16x8*)&Vt_buf[((size_t)(b * 16 + h) * 64 + d) * 2048 + t] = vv;
    }
  }
}

// ---------------------------------------------------------------------------
// gemm_out (R9 exact): out = A @ WoT^T + bo -> fp32. BM=128, BN=64, BK=64.
// ---------------------------------------------------------------------------
__global__ __launch_bounds__(256) void gemm_out(const bf16* __restrict__ X,
                                                const bf16* __restrict__ WT,
                                                const float* __restrict__ B,
                                                float* __restrict__ out) {
  __shared__ __align__(16) bf16 As[128 * 64];
  __shared__ __align__(16) bf16 Ws[64 * 64];
  const int tid = threadIdx.x;
  const int lane = tid & 63, w = tid >> 6;
  const int l15 = lane & 15, quad = lane >> 4;
  const int mBase = blockIdx.y * 128, nBase = blockIdx.x * 64;
  const int wm = (w >> 1) * 64, wn = (w & 1) * 32;

  const int r8 = tid >> 3;
  const int jg = ((tid & 7) ^ (r8 & 7)) * 8;
  const int sw = l15 & 7;

  f32x4 acc[4][2] = {};

  for (int k0 = 0; k0 < 1024; k0 += 64) {
    __syncthreads();
#pragma unroll
    for (int i = 0; i < 4; ++i)
      load_lds16(&X[(size_t)(mBase + r8 + i * 32) * 1024 + k0 + jg],
                 &As[(tid + i * 256) * 8]);
#pragma unroll
    for (int i = 0; i < 2; ++i)
      load_lds16(&WT[(size_t)(nBase + r8 + i * 32) * 1024 + k0 + jg],
                 &Ws[(tid + i * 256) * 8]);
    __syncthreads();

#pragma unroll
    for (int k2 = 0; k2 < 2; ++k2) {
      const int col = ((k2 * 4 + quad) ^ sw) * 8;
      bf16x8 a[4], bb[2];
#pragma unroll
      for (int mt = 0; mt < 4; ++mt)
        a[mt] = *(const bf16x8*)&As[(wm + mt * 16 + l15) * 64 + col];
#pragma unroll
      for (int nt = 0; nt < 2; ++nt)
        bb[nt] = *(const bf16x8*)&Ws[(wn + nt * 16 + l15) * 64 + col];
#pragma unroll
      for (int mt = 0; mt < 4; ++mt)
#pragma unroll
        for (int nt = 0; nt < 2; ++nt)
          acc[mt][nt] = MFMA16(a[mt], bb[nt], acc[mt][nt]);
    }
  }

#pragma unroll
  for (int nt = 0; nt < 2; ++nt) {
    const int n = nBase + wn + nt * 16 + l15;
    const float bias = B[n];
#pragma unroll
    for (int mt = 0; mt < 4; ++mt)
#pragma unroll
      for (int r = 0; r < 4; ++r) {
        const int m = mBase + wm + mt * 16 + quad * 4 + r;
        out[(size_t)m * 1024 + n] = acc[mt][nt][r] + bias;
      }
  }
}

// ---------------------------------------------------------------------------
// flash_attn (R9 exact): S^T/O^T form, fixed-reference softmax (m=0),
// per-lane scalar row sum; K/V via global_load_lds into swizzled flat LDS.
// ---------------------------------------------------------------------------
__global__ __launch_bounds__(256) void flash_attn(const bf16* __restrict__ Q,
                                                  const bf16* __restrict__ K,
                                                  const bf16* __restrict__ Vt,
                                                  const int* __restrict__ mask,
                                                  bf16* __restrict__ A) {
  __shared__ __align__(16) bf16 Ks[64 * 64];  // [key][d] swizzled
  __shared__ __align__(16) bf16 Vs[64 * 64];  // [d][key] swizzled
  __shared__ __align__(16) bf16 Ps[64 * 72];  // [q][key], wave-private rows
  __shared__ __align__(16) int msk[64];

  const int tid = threadIdx.x;
  const int lane = tid & 63, w = tid >> 6;
  const int l15 = lane & 15, quad = lane >> 4;
  const int bh = blockIdx.y;
  const int b = bh >> 4, h = bh & 15;
  const int qt = blockIdx.x * 64;

  const int r8 = tid >> 3;
  const int jg = ((tid & 7) ^ (r8 & 7)) * 8;
  const int sw = l15 & 7;

  const size_t qbase = ((size_t)bh * 2048 + qt + w * 16 + l15) * 64;
  const bf16x8 bq0 = *(const bf16x8*)&Q[qbase + quad * 8];
  const bf16x8 bq1 = *(const bf16x8*)&Q[qbase + 32 + quad * 8];

  f32x4 o[4] = {};
  float rs = 0.0f;

  for (int kt = 0; kt < 2048; kt += 64) {
    __syncthreads();
#pragma unroll
    for (int i = 0; i < 2; ++i) {
      const int row = r8 + i * 32;
      load_lds16(&K[((size_t)bh * 2048 + kt + row) * 64 + jg], &Ks[(tid + i * 256) * 8]);
      load_lds16(&Vt[((size_t)bh * 64 + row) * 2048 + kt + jg], &Vs[(tid + i * 256) * 8]);
    }
    if (tid < 64) msk[tid] = mask[b * 2048 + kt + tid];
    __syncthreads();

#pragma unroll
    for (int nt = 0; nt < 4; ++nt) {
      const bf16x8 ak0 = *(const bf16x8*)&Ks[(nt * 16 + l15) * 64 + ((quad ^ sw) * 8)];
      const bf16x8 ak1 = *(const bf16x8*)&Ks[(nt * 16 + l15) * 64 + (((4 + quad) ^ sw) * 8)];
      f32x4 s4 = {};
      s4 = MFMA16(ak0, bq0, s4);
      s4 = MFMA16(ak1, bq1, s4);
      const int4 mi = *(const int4*)&msk[nt * 16 + quad * 4];
      const float p0 = mi.x ? __expf(s4[0]) : 0.0f;
      const float p1 = mi.y ? __expf(s4[1]) : 0.0f;
      const float p2 = mi.z ? __expf(s4[2]) : 0.0f;
      const float p3 = mi.w ? __expf(s4[3]) : 0.0f;
      rs += (p0 + p1) + (p2 + p3);
      bf16x4 pk;
      pk[0] = (bf16)p0; pk[1] = (bf16)p1; pk[2] = (bf16)p2; pk[3] = (bf16)p3;
      *(bf16x4*)&Ps[(w * 16 + l15) * 72 + nt * 16 + quad * 4] = pk;
    }
    // No barrier: Ps rows wave-private, DS in-order per wave.

#pragma unroll
    for (int ks = 0; ks < 2; ++ks) {
      const bf16x8 bp = *(const bf16x8*)&Ps[(w * 16 + l15) * 72 + ks * 32 + quad * 8];
#pragma unroll
      for (int mt = 0; mt < 4; ++mt) {
        const bf16x8 av =
            *(const bf16x8*)&Vs[(mt * 16 + l15) * 64 + (((ks * 4 + quad) ^ sw) * 8)];
        o[mt] = MFMA16(av, bp, o[mt]);
      }
    }
  }

  rs += __shfl_xor(rs, 16);
  rs += __shfl_xor(rs, 32);
  const float inv = rs > 0.0f ? 1.0f / rs : 0.0f;

  const int t = qt + w * 16 + l15;
  const size_t base = ((size_t)b * 2048 + t) * 1024 + h * 64;
#pragma unroll
  for (int mt = 0; mt < 4; ++mt) {
    bf16x4 ov;
#pragma unroll
    for (int r = 0; r < 4; ++r) ov[r] = (bf16)(o[mt][r] * inv);
    *(bf16x4*)&A[base + mt * 16 + quad * 4] = ov;
  }
}

// ---------------------------------------------------------------------------
extern "C" void kernel_launch(void* const* d_in, const int* in_sizes, int n_in,
                              void* d_out, int out_size, void* d_ws, size_t ws_size,
                              hipStream_t stream) {
  const float* k = (const float*)d_in[0];
  const float* q = (const float*)d_in[1];
  const float* v = (const float*)d_in[2];
  const int* mask = (const int*)d_in[3];
  const float* Wk = (const float*)d_in[4];
  const float* bk = (const float*)d_in[5];
  const float* Wq = (const float*)d_in[6];
  const float* bq = (const float*)d_in[7];
  const float* Wv = (const float*)d_in[8];
  const float* bv = (const float*)d_in[9];
  const float* Wo = (const float*)d_in[10];
  const float* bo = (const float*)d_in[11];

  const size_t ELEMS = (size_t)4 * 1024 * 1024;
  const size_t WELEMS = (size_t)1024 * 1024;

  bf16* kb = (bf16*)d_ws;
  bf16* qb = kb + ELEMS;
  bf16* vb = qb + ELEMS;
  bf16* WkT = vb + ELEMS;
  bf16* WqT = WkT + WELEMS;
  bf16* WvT = WqT + WELEMS;
  bf16* WoT = WvT + WELEMS;

  bf16* K_buf = (bf16*)d_in[0];
  bf16* Q_buf = (bf16*)d_in[0] + ELEMS;
  bf16* Vt_buf = (bf16*)d_in[2];
  bf16* A_buf = (bf16*)d_in[2] + ELEMS;

  convert3<<<6144, 256, 0, stream>>>(k, q, v, kb, qb, vb);
  transposeW<<<dim3(16, 16, 4), 256, 0, stream>>>(Wk, Wq, Wv, Wo,
                                                  WkT, WqT, WvT, WoT);
  gemm_qkv<<<dim3(16, 32, 3), 256, 0, stream>>>(kb, vb, qb, WkT, WvT, WqT,
                                                bk, bv, bq, K_buf, Vt_buf, Q_buf);
  flash_attn<<<dim3(32, 32), 256, 0, stream>>>(Q_buf, K_buf, Vt_buf, mask, A_buf);
  gemm_out<<<dim3(16, 32), 256, 0, stream>>>(A_buf, WoT, bo, (float*)d_out);
}